// Round 1
// baseline (8335.084 us; speedup 1.0000x reference)
//
#include <hip/hip_runtime.h>
#include <math.h>

#define N_PTS 262144
#define D 128
#define K_CL 120
#define KP 128      // padded cluster count
#define MT 128      // points per block tile
#define KC 32       // k-chunk
#define LST 36      // padded LDS row stride (floats); 36*4=144 B, 16B-aligned rows

// ---------------------------------------------------------------------------
// init: c = x[:120] for both features, plus csq = rowwise sum of squares
// grid 240 x 128
__global__ __launch_bounds__(128) void init_kernel(
    const float* __restrict__ f1, const float* __restrict__ f2,
    float* __restrict__ c1, float* __restrict__ c2,
    float* __restrict__ csq1, float* __restrict__ csq2)
{
    int b = blockIdx.x;
    const float* src = (b < K_CL) ? f1 : f2;
    float* dst       = (b < K_CL) ? c1 : c2;
    float* dsq       = (b < K_CL) ? csq1 : csq2;
    int j = (b < K_CL) ? b : (b - K_CL);
    int d = threadIdx.x;
    float v = src[(long)j * D + d];
    dst[(long)j * D + d] = v;
    float sq = v * v;
#pragma unroll
    for (int w = 1; w < 64; w <<= 1) sq += __shfl_xor(sq, w, 64);
    __shared__ float tmp[2];
    if ((d & 63) == 0) tmp[d >> 6] = sq;
    __syncthreads();
    if (d == 0) dsq[j] = tmp[0] + tmp[1];
}

// ---------------------------------------------------------------------------
// assign: cl[i] = argmin_j csq[j] - 2*x[i].c[j]   (x_sq constant -> dropped)
// grid 2048 x 256. Block tile: 128 points x 128 clusters(pad), 8x8 per thread.
__global__ __launch_bounds__(256) void assign_kernel(
    const float* __restrict__ x, const float* __restrict__ c,
    const float* __restrict__ csq, int* __restrict__ cl)
{
    __shared__ float xs[MT * LST];
    __shared__ float cs[KP * LST];
    __shared__ float scs[KP];

    int tid = threadIdx.x;
    int tx = tid & 15, ty = tid >> 4;
    long base = (long)blockIdx.x * MT;

    if (tid < KP) scs[tid] = (tid < K_CL) ? csq[tid] : 3.0e38f;

    float acc[8][8];
#pragma unroll
    for (int i = 0; i < 8; i++)
#pragma unroll
        for (int j = 0; j < 8; j++) acc[i][j] = 0.f;

    for (int kc = 0; kc < D; kc += KC) {
        __syncthreads();
#pragma unroll
        for (int l = 0; l < 4; l++) {
            int idx = tid + 256 * l;          // 0..1023
            int m = idx >> 3, k4 = idx & 7;
            float4 v = *(const float4*)(x + (base + m) * D + kc + k4 * 4);
            *(float4*)(xs + m * LST + k4 * 4) = v;
        }
#pragma unroll
        for (int l = 0; l < 4; l++) {
            int idx = tid + 256 * l;
            int n = idx >> 3, k4 = idx & 7;
            float4 v = make_float4(0.f, 0.f, 0.f, 0.f);
            if (n < K_CL) v = *(const float4*)(c + (long)n * D + kc + k4 * 4);
            *(float4*)(cs + n * LST + k4 * 4) = v;
        }
        __syncthreads();
#pragma unroll
        for (int k4 = 0; k4 < KC; k4 += 4) {
            float4 xv[8], cv[8];
#pragma unroll
            for (int i = 0; i < 8; i++) xv[i] = *(const float4*)(xs + (ty + 16 * i) * LST + k4);
#pragma unroll
            for (int j = 0; j < 8; j++) cv[j] = *(const float4*)(cs + (tx + 16 * j) * LST + k4);
#pragma unroll
            for (int i = 0; i < 8; i++)
#pragma unroll
                for (int j = 0; j < 8; j++)
                    acc[i][j] += xv[i].x * cv[j].x + xv[i].y * cv[j].y +
                                 xv[i].z * cv[j].z + xv[i].w * cv[j].w;
        }
    }

    // epilogue: argmin over 128 clusters per point (butterfly over tx lanes)
#pragma unroll
    for (int i = 0; i < 8; i++) {
        float best = 3.9e38f; int bidx = 0;
#pragma unroll
        for (int j = 0; j < 8; j++) {
            int n = tx + 16 * j;
            float s = scs[n] - 2.f * acc[i][j];
            if (s < best) { best = s; bidx = n; }
        }
#pragma unroll
        for (int w = 1; w < 16; w <<= 1) {
            float ov = __shfl_xor(best, w, 64);
            int oi = __shfl_xor(bidx, w, 64);
            if (ov < best || (ov == best && oi < bidx)) { best = ov; bidx = oi; }
        }
        if (tx == 0) cl[base + ty + 16 * i] = bidx;
    }
}

// ---------------------------------------------------------------------------
// accumulate: per-block LDS-privatized scatter-add of x rows by cluster
// grid 512 x 256, 512 points per block
__global__ __launch_bounds__(256) void accum_kernel(
    const float* __restrict__ x, const int* __restrict__ cl,
    float* __restrict__ sums, float* __restrict__ counts)
{
    __shared__ float s_s[K_CL * D];
    __shared__ float s_c[K_CL];
    int tid = threadIdx.x;
    for (int i = tid; i < K_CL * D; i += 256) s_s[i] = 0.f;
    if (tid < K_CL) s_c[tid] = 0.f;
    __syncthreads();

    const int PPB = N_PTS / 512;              // 512 points
    long base = (long)blockIdx.x * PPB;
    int d4 = tid & 31, sub = tid >> 5;        // 8 points in flight per step
#pragma unroll 4
    for (int p = sub; p < PPB; p += 8) {
        long pt = base + p;
        int cc = cl[pt];
        float4 v = *(const float4*)(x + pt * D + d4 * 4);
        int off = cc * D + d4 * 4;
        atomicAdd(&s_s[off + 0], v.x);
        atomicAdd(&s_s[off + 1], v.y);
        atomicAdd(&s_s[off + 2], v.z);
        atomicAdd(&s_s[off + 3], v.w);
        if (d4 == 0) atomicAdd(&s_c[cc], 1.0f);
    }
    __syncthreads();
    for (int i = tid; i < K_CL * D; i += 256) unsafeAtomicAdd(&sums[i], s_s[i]);
    if (tid < K_CL) unsafeAtomicAdd(&counts[tid], s_c[tid]);
}

// ---------------------------------------------------------------------------
// update: c = sums / max(counts,1-if-0); csq = rowwise sumsq.  grid 120 x 128
__global__ __launch_bounds__(128) void update_kernel(
    float* __restrict__ c, float* __restrict__ csq,
    const float* __restrict__ sums, const float* __restrict__ counts)
{
    int j = blockIdx.x, d = threadIdx.x;
    float cnt = counts[j];
    float div = (cnt == 0.f) ? 1.f : cnt;
    float v = sums[j * D + d] / div;
    c[j * D + d] = v;
    float sq = v * v;
#pragma unroll
    for (int w = 1; w < 64; w <<= 1) sq += __shfl_xor(sq, w, 64);
    __shared__ float tmp[2];
    if ((d & 63) == 0) tmp[d >> 6] = sq;
    __syncthreads();
    if (d == 0) csq[j] = tmp[0] + tmp[1];
}

// ---------------------------------------------------------------------------
// cross-entropy: loss_i = logsumexp(x_i.C^T/T) - (x_i.c[label]/T); sum into acc
// grid 2048 x 256, same GEMM tiling as assign
__global__ __launch_bounds__(256) void ce_kernel(
    const float* __restrict__ x, const float* __restrict__ c,
    const int* __restrict__ cl, float* __restrict__ acc_out)
{
    __shared__ float xs[MT * LST];
    __shared__ float cs[KP * LST];

    int tid = threadIdx.x;
    int tx = tid & 15, ty = tid >> 4;
    long base = (long)blockIdx.x * MT;

    float acc[8][8];
#pragma unroll
    for (int i = 0; i < 8; i++)
#pragma unroll
        for (int j = 0; j < 8; j++) acc[i][j] = 0.f;

    for (int kc = 0; kc < D; kc += KC) {
        __syncthreads();
#pragma unroll
        for (int l = 0; l < 4; l++) {
            int idx = tid + 256 * l;
            int m = idx >> 3, k4 = idx & 7;
            float4 v = *(const float4*)(x + (base + m) * D + kc + k4 * 4);
            *(float4*)(xs + m * LST + k4 * 4) = v;
        }
#pragma unroll
        for (int l = 0; l < 4; l++) {
            int idx = tid + 256 * l;
            int n = idx >> 3, k4 = idx & 7;
            float4 v = make_float4(0.f, 0.f, 0.f, 0.f);
            if (n < K_CL) v = *(const float4*)(c + (long)n * D + kc + k4 * 4);
            *(float4*)(cs + n * LST + k4 * 4) = v;
        }
        __syncthreads();
#pragma unroll
        for (int k4 = 0; k4 < KC; k4 += 4) {
            float4 xv[8], cv[8];
#pragma unroll
            for (int i = 0; i < 8; i++) xv[i] = *(const float4*)(xs + (ty + 16 * i) * LST + k4);
#pragma unroll
            for (int j = 0; j < 8; j++) cv[j] = *(const float4*)(cs + (tx + 16 * j) * LST + k4);
#pragma unroll
            for (int i = 0; i < 8; i++)
#pragma unroll
                for (int j = 0; j < 8; j++)
                    acc[i][j] += xv[i].x * cv[j].x + xv[i].y * cv[j].y +
                                 xv[i].z * cv[j].z + xv[i].w * cv[j].w;
        }
    }

    const float invT = 2.5f;   // 1/0.4
    float local_loss = 0.f;
#pragma unroll
    for (int i = 0; i < 8; i++) {
        int label = cl[base + ty + 16 * i];
        float L[8];
        float lmax = -3.0e38f;
        float lsel = 0.f;
#pragma unroll
        for (int j = 0; j < 8; j++) {
            int n = tx + 16 * j;
            if (n < K_CL) {
                L[j] = acc[i][j] * invT;
                lmax = fmaxf(lmax, L[j]);
                if (n == label) lsel = L[j];
            } else {
                L[j] = -3.0e38f;
            }
        }
#pragma unroll
        for (int w = 1; w < 16; w <<= 1) lmax = fmaxf(lmax, __shfl_xor(lmax, w, 64));
        float sexp = 0.f;
#pragma unroll
        for (int j = 0; j < 8; j++) {
            int n = tx + 16 * j;
            if (n < K_CL) sexp += expf(L[j] - lmax);
        }
#pragma unroll
        for (int w = 1; w < 16; w <<= 1) {
            sexp += __shfl_xor(sexp, w, 64);
            lsel += __shfl_xor(lsel, w, 64);
        }
        if (tx == 0) local_loss += (lmax + logf(sexp)) - lsel;
    }
    if (tx == 0) unsafeAtomicAdd(acc_out, local_loss);
}

// ---------------------------------------------------------------------------
__global__ void final_kernel(const float* __restrict__ lacc, float* __restrict__ out)
{
    out[0] = (lacc[0] + lacc[1]) * (0.5f / (float)N_PTS);
}

// ---------------------------------------------------------------------------
extern "C" void kernel_launch(void* const* d_in, const int* in_sizes, int n_in,
                              void* d_out, int out_size, void* d_ws, size_t ws_size,
                              hipStream_t stream)
{
    const float* f1 = (const float*)d_in[0];
    const float* f2 = (const float*)d_in[1];
    float* out = (float*)d_out;

    char* ws = (char*)d_ws;
    float* c1   = (float*)ws; ws += K_CL * D * sizeof(float);   // 61440
    float* c2   = (float*)ws; ws += K_CL * D * sizeof(float);
    float* csq1 = (float*)ws; ws += 128 * sizeof(float);
    float* csq2 = (float*)ws; ws += 128 * sizeof(float);
    float* sums = (float*)ws; ws += K_CL * D * sizeof(float);
    float* cnts = (float*)ws; ws += 128 * sizeof(float);
    float* lacc = (float*)ws; ws += 64;
    int* cl1    = (int*)ws;   ws += (size_t)N_PTS * sizeof(int);
    int* cl2    = (int*)ws;

    hipMemsetAsync(lacc, 0, 2 * sizeof(float), stream);
    init_kernel<<<240, 128, 0, stream>>>(f1, f2, c1, c2, csq1, csq2);

    for (int it = 0; it < 5; ++it) {
        // feature 1
        assign_kernel<<<N_PTS / MT, 256, 0, stream>>>(f1, c1, csq1, cl1);
        hipMemsetAsync(sums, 0, K_CL * D * sizeof(float), stream);
        hipMemsetAsync(cnts, 0, 128 * sizeof(float), stream);
        accum_kernel<<<512, 256, 0, stream>>>(f1, cl1, sums, cnts);
        update_kernel<<<K_CL, 128, 0, stream>>>(c1, csq1, sums, cnts);
        // feature 2
        assign_kernel<<<N_PTS / MT, 256, 0, stream>>>(f2, c2, csq2, cl2);
        hipMemsetAsync(sums, 0, K_CL * D * sizeof(float), stream);
        hipMemsetAsync(cnts, 0, 128 * sizeof(float), stream);
        accum_kernel<<<512, 256, 0, stream>>>(f2, cl2, sums, cnts);
        update_kernel<<<K_CL, 128, 0, stream>>>(c2, csq2, sums, cnts);
    }

    ce_kernel<<<N_PTS / MT, 256, 0, stream>>>(f1, c2, cl2, lacc + 0);
    ce_kernel<<<N_PTS / MT, 256, 0, stream>>>(f2, c1, cl1, lacc + 1);
    final_kernel<<<1, 1, 0, stream>>>(lacc, out);
}

// Round 2
// 2602.962 us; speedup vs baseline: 3.2022x; 3.2022x over previous
//
#include <hip/hip_runtime.h>
#include <math.h>

#define N_PTS 262144
#define D 128
#define K_CL 120
#define LSTRIDE 72   // LDS row stride in bf16 units (144 B = 36 words): frag reads 2-way (free)

typedef short bf16x8 __attribute__((ext_vector_type(8)));
typedef float floatx4 __attribute__((ext_vector_type(4)));

__device__ __forceinline__ unsigned short f2bf(float f) {
    unsigned u = __float_as_uint(f);
    u += 0x7fffu + ((u >> 16) & 1u);   // RNE
    return (unsigned short)(u >> 16);
}

// ---------------------------------------------------------------------------
// init: cb = bf16(x[:120]), csq = rowwise sumsq (fp32).  grid 240 x 128
__global__ __launch_bounds__(128) void init_kernel(
    const float* __restrict__ f1, const float* __restrict__ f2,
    unsigned short* __restrict__ cb1, unsigned short* __restrict__ cb2,
    float* __restrict__ csq1, float* __restrict__ csq2)
{
    int b = blockIdx.x;
    const float* src = (b < K_CL) ? f1 : f2;
    unsigned short* cb = (b < K_CL) ? cb1 : cb2;
    float* dsq          = (b < K_CL) ? csq1 : csq2;
    int j = (b < K_CL) ? b : (b - K_CL);
    int d = threadIdx.x;
    float v = src[(long)j * D + d];
    cb[j * D + d] = f2bf(v);
    float sq = v * v;
#pragma unroll
    for (int w = 1; w < 64; w <<= 1) sq += __shfl_xor(sq, w, 64);
    __shared__ float tmp[2];
    if ((d & 63) == 0) tmp[d >> 6] = sq;
    __syncthreads();
    if (d == 0) dsq[j] = tmp[0] + tmp[1];
}

// ---------------------------------------------------------------------------
// MFMA GEMM: S[m][n] = x[m].c[n]  (128 points x 128 clusters per block, K=128)
// CE=false: argmin epilogue -> cl.   CE=true: logsumexp epilogue -> part[blk].
// grid 2048 x 256 (4 waves; wave w owns point rows w*32..w*32+31)
template<bool CE>
__global__ __launch_bounds__(256) void gemm_kernel(
    const float* __restrict__ x, const unsigned short* __restrict__ cb,
    const float* __restrict__ csq, int* __restrict__ cl,
    float* __restrict__ part)
{
    __shared__ unsigned short xs[128 * LSTRIDE];
    __shared__ unsigned short cs[128 * LSTRIDE];
    __shared__ float scs[128];
    __shared__ float red[4];

    int tid  = threadIdx.x;
    int lane = tid & 63, wave = tid >> 6;
    int q = lane >> 4, c16 = lane & 15;
    long base = (long)blockIdx.x * 128;

    if (!CE) {
        if (tid < 128) scs[tid] = (tid < K_CL) ? csq[tid] : 3.0e38f;
    }

    floatx4 acc[2][8];
#pragma unroll
    for (int ri = 0; ri < 2; ri++)
#pragma unroll
        for (int cj = 0; cj < 8; cj++) acc[ri][cj] = (floatx4){0.f, 0.f, 0.f, 0.f};

    for (int kc = 0; kc < D; kc += 64) {
        __syncthreads();
        // stage x chunk: 128 rows x 64 cols, fp32 -> bf16 (coalesced float4)
#pragma unroll
        for (int l = 0; l < 8; l++) {
            int idx = tid + 256 * l;            // 0..2047
            int m = idx >> 4, k4 = idx & 15;    // row, float4-chunk in row
            float4 v = *(const float4*)(x + (base + m) * D + kc + k4 * 4);
            uint2 w;
            w.x = (unsigned)f2bf(v.x) | ((unsigned)f2bf(v.y) << 16);
            w.y = (unsigned)f2bf(v.z) | ((unsigned)f2bf(v.w) << 16);
            *(uint2*)(&xs[m * LSTRIDE + k4 * 4]) = w;
        }
        // stage c chunk: bf16 rows; pad clusters 120..127 with zeros
#pragma unroll
        for (int l = 0; l < 8; l++) {
            int idx = tid + 256 * l;
            int n = idx >> 4, k4 = idx & 15;
            uint2 w = make_uint2(0u, 0u);
            if (n < K_CL) w = *(const uint2*)(cb + n * D + kc + k4 * 4);
            *(uint2*)(&cs[n * LSTRIDE + k4 * 4]) = w;
        }
        __syncthreads();
#pragma unroll
        for (int s = 0; s < 2; s++) {
            int kk = s * 32 + q * 8;
            bf16x8 a[2], b[8];
#pragma unroll
            for (int ri = 0; ri < 2; ri++)
                a[ri] = *(const bf16x8*)(&xs[(wave * 32 + ri * 16 + c16) * LSTRIDE + kk]);
#pragma unroll
            for (int cj = 0; cj < 8; cj++)
                b[cj] = *(const bf16x8*)(&cs[(cj * 16 + c16) * LSTRIDE + kk]);
#pragma unroll
            for (int ri = 0; ri < 2; ri++)
#pragma unroll
                for (int cj = 0; cj < 8; cj++)
                    acc[ri][cj] = __builtin_amdgcn_mfma_f32_16x16x32_bf16(
                        a[ri], b[cj], acc[ri][cj], 0, 0, 0);
        }
    }

    // C/D layout: cluster n = cj*16 + c16 ; point m = wave*32 + ri*16 + q*4 + reg
    if (!CE) {
#pragma unroll
        for (int ri = 0; ri < 2; ri++) {
#pragma unroll
            for (int reg = 0; reg < 4; reg++) {
                float best = 3.9e38f; int bi = 0;
#pragma unroll
                for (int cj = 0; cj < 8; cj++) {
                    int n = cj * 16 + c16;
                    float s = scs[n] - 2.f * acc[ri][cj][reg];
                    if (s < best) { best = s; bi = n; }
                }
#pragma unroll
                for (int w = 1; w < 16; w <<= 1) {
                    float ov = __shfl_xor(best, w, 64);
                    int   oi = __shfl_xor(bi,   w, 64);
                    if (ov < best || (ov == best && oi < bi)) { best = ov; bi = oi; }
                }
                if (c16 == 0) cl[base + wave * 32 + ri * 16 + q * 4 + reg] = bi;
            }
        }
    } else {
        const float invT = 2.5f;
        float th_loss = 0.f;
#pragma unroll
        for (int ri = 0; ri < 2; ri++) {
#pragma unroll
            for (int reg = 0; reg < 4; reg++) {
                long m = base + wave * 32 + ri * 16 + q * 4 + reg;
                int lbl = cl[m];
                float L[8];
                float lmax = -3.0e38f;
#pragma unroll
                for (int cj = 0; cj < 8; cj++) {
                    int n = cj * 16 + c16;
                    L[cj] = (n < K_CL) ? invT * acc[ri][cj][reg] : -3.0e38f;
                    lmax = fmaxf(lmax, L[cj]);
                }
#pragma unroll
                for (int w = 1; w < 16; w <<= 1) lmax = fmaxf(lmax, __shfl_xor(lmax, w, 64));
                float se = 0.f, lsel = 0.f;
#pragma unroll
                for (int cj = 0; cj < 8; cj++) {
                    int n = cj * 16 + c16;
                    if (n < K_CL) {
                        se += __expf(L[cj] - lmax);
                        if (n == lbl) lsel = L[cj];
                    }
                }
#pragma unroll
                for (int w = 1; w < 16; w <<= 1) {
                    se   += __shfl_xor(se,   w, 64);
                    lsel += __shfl_xor(lsel, w, 64);
                }
                if (c16 == 0) th_loss += (lmax + __logf(se)) - lsel;
            }
        }
#pragma unroll
        for (int w = 1; w < 64; w <<= 1) th_loss += __shfl_xor(th_loss, w, 64);
        if (lane == 0) red[wave] = th_loss;
        __syncthreads();
        if (tid == 0) part[blockIdx.x] = red[0] + red[1] + red[2] + red[3];
    }
}

// ---------------------------------------------------------------------------
// accumulate: LDS-privatized scatter-add; lane d owns dims {d, d+32, d+64, d+96}
// -> LDS atomic bank == lane (conflict-free).  grid 256 x 256, 1024 pts/block
__global__ __launch_bounds__(256) void accum_kernel(
    const float* __restrict__ x, const int* __restrict__ cl,
    float* __restrict__ sums, float* __restrict__ counts)
{
    __shared__ float s_s[K_CL * D];
    __shared__ float s_c[K_CL];
    int tid = threadIdx.x;
    for (int i = tid; i < K_CL * D; i += 256) s_s[i] = 0.f;
    if (tid < K_CL) s_c[tid] = 0.f;
    __syncthreads();

    const int PPB = N_PTS / 256;          // 1024
    long base = (long)blockIdx.x * PPB;
    int d4 = tid & 31, sub = tid >> 5;    // 8 points in flight per step
#pragma unroll 4
    for (int p = sub; p < PPB; p += 8) {
        long pt = base + p;
        int cc = cl[pt];
        float v0 = x[pt * D + d4 +  0];
        float v1 = x[pt * D + d4 + 32];
        float v2 = x[pt * D + d4 + 64];
        float v3 = x[pt * D + d4 + 96];
        int off = cc * D + d4;
        atomicAdd(&s_s[off +  0], v0);
        atomicAdd(&s_s[off + 32], v1);
        atomicAdd(&s_s[off + 64], v2);
        atomicAdd(&s_s[off + 96], v3);
        if (d4 == 0) atomicAdd(&s_c[cc], 1.0f);
    }
    __syncthreads();
    for (int i = tid; i < K_CL * D; i += 256) unsafeAtomicAdd(&sums[i], s_s[i]);
    if (tid < K_CL) unsafeAtomicAdd(&counts[tid], s_c[tid]);
}

// ---------------------------------------------------------------------------
// update: c = sums/max(cnt, 1-if-0); emit bf16 copy + csq; zero sums/cnts for
// next iteration (replaces per-iter memsets).  grid 120 x 128
__global__ __launch_bounds__(128) void update_kernel(
    unsigned short* __restrict__ cb, float* __restrict__ csq,
    float* __restrict__ sums, float* __restrict__ counts)
{
    int j = blockIdx.x, d = threadIdx.x;
    float cnt = counts[j];
    float div = (cnt == 0.f) ? 1.f : cnt;
    float v = sums[j * D + d] / div;
    cb[j * D + d] = f2bf(v);
    sums[j * D + d] = 0.f;                 // own element only: no race
    float sq = v * v;
#pragma unroll
    for (int w = 1; w < 64; w <<= 1) sq += __shfl_xor(sq, w, 64);
    __shared__ float tmp[2];
    if ((d & 63) == 0) tmp[d >> 6] = sq;
    __syncthreads();                       // also orders counts[j] read vs zero
    if (d == 0) { csq[j] = tmp[0] + tmp[1]; counts[j] = 0.f; }
}

// ---------------------------------------------------------------------------
// final: sum 4096 CE block-partials, scale.  1 block x 256
__global__ __launch_bounds__(256) void final_kernel(
    const float* __restrict__ part, float* __restrict__ out)
{
    int tid = threadIdx.x;
    float s = 0.f;
#pragma unroll
    for (int k = 0; k < 16; k++) s += part[tid + 256 * k];
#pragma unroll
    for (int w = 1; w < 64; w <<= 1) s += __shfl_xor(s, w, 64);
    __shared__ float tmp[4];
    if ((tid & 63) == 0) tmp[tid >> 6] = s;
    __syncthreads();
    if (tid == 0)
        out[0] = (tmp[0] + tmp[1] + tmp[2] + tmp[3]) * (0.5f / (float)N_PTS);
}

// ---------------------------------------------------------------------------
extern "C" void kernel_launch(void* const* d_in, const int* in_sizes, int n_in,
                              void* d_out, int out_size, void* d_ws, size_t ws_size,
                              hipStream_t stream)
{
    const float* f1 = (const float*)d_in[0];
    const float* f2 = (const float*)d_in[1];
    float* out = (float*)d_out;

    char* ws = (char*)d_ws;
    unsigned short* cb1 = (unsigned short*)ws; ws += K_CL * D * sizeof(short);  // 30720
    unsigned short* cb2 = (unsigned short*)ws; ws += K_CL * D * sizeof(short);
    float* csq1 = (float*)ws; ws += 128 * sizeof(float);
    float* csq2 = (float*)ws; ws += 128 * sizeof(float);
    float* sums = (float*)ws; ws += K_CL * D * sizeof(float);   // sums+cnts contiguous
    float* cnts = (float*)ws; ws += 128 * sizeof(float);        // -> single memset
    float* part = (float*)ws; ws += 4096 * sizeof(float);
    int* cl1    = (int*)ws;   ws += (size_t)N_PTS * sizeof(int);
    int* cl2    = (int*)ws;

    hipMemsetAsync(sums, 0, (K_CL * D + 128) * sizeof(float), stream);
    init_kernel<<<240, 128, 0, stream>>>(f1, f2, cb1, cb2, csq1, csq2);

    for (int it = 0; it < 5; ++it) {
        assign: ;
        gemm_kernel<false><<<N_PTS / 128, 256, 0, stream>>>(f1, cb1, csq1, cl1, nullptr);
        accum_kernel<<<256, 256, 0, stream>>>(f1, cl1, sums, cnts);
        update_kernel<<<K_CL, 128, 0, stream>>>(cb1, csq1, sums, cnts);

        gemm_kernel<false><<<N_PTS / 128, 256, 0, stream>>>(f2, cb2, csq2, cl2, nullptr);
        accum_kernel<<<256, 256, 0, stream>>>(f2, cl2, sums, cnts);
        update_kernel<<<K_CL, 128, 0, stream>>>(cb2, csq2, sums, cnts);
    }

    gemm_kernel<true><<<N_PTS / 128, 256, 0, stream>>>(f1, cb2, nullptr, cl2, part);
    gemm_kernel<true><<<N_PTS / 128, 256, 0, stream>>>(f2, cb1, nullptr, cl1, part + 2048);
    final_kernel<<<1, 256, 0, stream>>>(part, out);
}

// Round 3
// 1303.455 us; speedup vs baseline: 6.3946x; 1.9970x over previous
//
#include <hip/hip_runtime.h>
#include <math.h>

#define N_PTS 262144
#define D 128
#define K_CL 120
#define LST 72    // assign/CE LDS stride (bf16) for 64-col chunks
#define AST 140   // accum LDS stride (bf16) for full 128-col rows; 70 words ->
                  // k-major u16 frag reads land ~2-way/bank (free, m136)
#define TPB_ACC 4 // point-tiles per accum block (grid 512 = 2 blocks/CU)

typedef short bf16x8 __attribute__((ext_vector_type(8)));
typedef float floatx4 __attribute__((ext_vector_type(4)));

__device__ __forceinline__ unsigned short f2bf(float f) {
    unsigned u = __float_as_uint(f);
    u += 0x7fffu + ((u >> 16) & 1u);   // RNE
    return (unsigned short)(u >> 16);
}

// ---------------------------------------------------------------------------
// convert: fp32 features -> bf16 copies (runs once; amortized over 12 GEMM
// dispatches that then fetch half the bytes).  grid 2048 x 256
__global__ __launch_bounds__(256) void convert_kernel(
    const float* __restrict__ f1, const float* __restrict__ f2,
    unsigned short* __restrict__ xb1, unsigned short* __restrict__ xb2)
{
    const int TOT = N_PTS * D / 4;           // float4 units per feature
    int i = blockIdx.x * 256 + threadIdx.x;  // stride 524288
#pragma unroll 4
    for (int it = 0; it < TOT; it += 524288) {
        int idx = it + i;
        float4 v = ((const float4*)f1)[idx];
        uint2 w;
        w.x = (unsigned)f2bf(v.x) | ((unsigned)f2bf(v.y) << 16);
        w.y = (unsigned)f2bf(v.z) | ((unsigned)f2bf(v.w) << 16);
        ((uint2*)xb1)[idx] = w;
        float4 u = ((const float4*)f2)[idx];
        uint2 t;
        t.x = (unsigned)f2bf(u.x) | ((unsigned)f2bf(u.y) << 16);
        t.y = (unsigned)f2bf(u.z) | ((unsigned)f2bf(u.w) << 16);
        ((uint2*)xb2)[idx] = t;
    }
}

// ---------------------------------------------------------------------------
// init: cb = bf16(x[:120]), csq = rowwise sumsq (fp32).  grid 240 x 128
__global__ __launch_bounds__(128) void init_kernel(
    const float* __restrict__ f1, const float* __restrict__ f2,
    unsigned short* __restrict__ cb1, unsigned short* __restrict__ cb2,
    float* __restrict__ csq1, float* __restrict__ csq2)
{
    int b = blockIdx.x;
    const float* src = (b < K_CL) ? f1 : f2;
    unsigned short* cb = (b < K_CL) ? cb1 : cb2;
    float* dsq          = (b < K_CL) ? csq1 : csq2;
    int j = (b < K_CL) ? b : (b - K_CL);
    int d = threadIdx.x;
    float v = src[(long)j * D + d];
    cb[j * D + d] = f2bf(v);
    float sq = v * v;
#pragma unroll
    for (int w = 1; w < 64; w <<= 1) sq += __shfl_xor(sq, w, 64);
    __shared__ float tmp[2];
    if ((d & 63) == 0) tmp[d >> 6] = sq;
    __syncthreads();
    if (d == 0) dsq[j] = tmp[0] + tmp[1];
}

// ---------------------------------------------------------------------------
// MFMA GEMM: S[m][n] = x[m].c[n]  (128 points x 128 clusters, K=128)
// CE=false: argmin -> cl.   CE=true: logsumexp -> part[blk].
// BF: stage from bf16 copy (xb) vs fp32 (xf) with inline convert.
template<bool CE, bool BF>
__global__ __launch_bounds__(256) void gemm_kernel(
    const float* __restrict__ xf, const unsigned short* __restrict__ xb,
    const unsigned short* __restrict__ cb,
    const float* __restrict__ csq, int* __restrict__ cl,
    float* __restrict__ part)
{
    __shared__ unsigned short xs[128 * LST];
    __shared__ unsigned short cs[128 * LST];
    __shared__ float scs[128];
    __shared__ float red[4];

    int tid  = threadIdx.x;
    int lane = tid & 63, wave = tid >> 6;
    int q = lane >> 4, c16 = lane & 15;
    long base = (long)blockIdx.x * 128;

    if (!CE) {
        if (tid < 128) scs[tid] = (tid < K_CL) ? csq[tid] : 3.0e38f;
    }

    floatx4 acc[2][8];
#pragma unroll
    for (int ri = 0; ri < 2; ri++)
#pragma unroll
        for (int cj = 0; cj < 8; cj++) acc[ri][cj] = (floatx4){0.f, 0.f, 0.f, 0.f};

    for (int kc = 0; kc < D; kc += 64) {
        __syncthreads();
        // stage x chunk: 128 rows x 64 cols
#pragma unroll
        for (int l = 0; l < 8; l++) {
            int idx = tid + 256 * l;            // 0..2047
            int m = idx >> 4, k4 = idx & 15;
            uint2 w;
            if (BF) {
                w = *(const uint2*)(xb + (base + m) * D + kc + k4 * 4);
            } else {
                float4 v = *(const float4*)(xf + (base + m) * D + kc + k4 * 4);
                w.x = (unsigned)f2bf(v.x) | ((unsigned)f2bf(v.y) << 16);
                w.y = (unsigned)f2bf(v.z) | ((unsigned)f2bf(v.w) << 16);
            }
            *(uint2*)(&xs[m * LST + k4 * 4]) = w;
        }
        // stage c chunk; pad clusters 120..127 with zeros
#pragma unroll
        for (int l = 0; l < 8; l++) {
            int idx = tid + 256 * l;
            int n = idx >> 4, k4 = idx & 15;
            uint2 w = make_uint2(0u, 0u);
            if (n < K_CL) w = *(const uint2*)(cb + n * D + kc + k4 * 4);
            *(uint2*)(&cs[n * LST + k4 * 4]) = w;
        }
        __syncthreads();
#pragma unroll
        for (int s = 0; s < 2; s++) {
            int kk = s * 32 + q * 8;
            bf16x8 a[2], b[8];
#pragma unroll
            for (int ri = 0; ri < 2; ri++)
                a[ri] = *(const bf16x8*)(&xs[(wave * 32 + ri * 16 + c16) * LST + kk]);
#pragma unroll
            for (int cj = 0; cj < 8; cj++)
                b[cj] = *(const bf16x8*)(&cs[(cj * 16 + c16) * LST + kk]);
#pragma unroll
            for (int ri = 0; ri < 2; ri++)
#pragma unroll
                for (int cj = 0; cj < 8; cj++)
                    acc[ri][cj] = __builtin_amdgcn_mfma_f32_16x16x32_bf16(
                        a[ri], b[cj], acc[ri][cj], 0, 0, 0);
        }
    }

    // C/D: cluster n = cj*16 + c16 ; point m = wave*32 + ri*16 + q*4 + reg
    if (!CE) {
#pragma unroll
        for (int ri = 0; ri < 2; ri++) {
#pragma unroll
            for (int reg = 0; reg < 4; reg++) {
                float best = 3.9e38f; int bi = 0;
#pragma unroll
                for (int cj = 0; cj < 8; cj++) {
                    int n = cj * 16 + c16;
                    float s = scs[n] - 2.f * acc[ri][cj][reg];
                    if (s < best) { best = s; bi = n; }
                }
#pragma unroll
                for (int w = 1; w < 16; w <<= 1) {
                    float ov = __shfl_xor(best, w, 64);
                    int   oi = __shfl_xor(bi,   w, 64);
                    if (ov < best || (ov == best && oi < bi)) { best = ov; bi = oi; }
                }
                if (c16 == 0) cl[base + wave * 32 + ri * 16 + q * 4 + reg] = bi;
            }
        }
    } else {
        const float invT = 2.5f;
        float th_loss = 0.f;
#pragma unroll
        for (int ri = 0; ri < 2; ri++) {
#pragma unroll
            for (int reg = 0; reg < 4; reg++) {
                long m = base + wave * 32 + ri * 16 + q * 4 + reg;
                int lbl = cl[m];
                float L[8];
                float lmax = -3.0e38f;
#pragma unroll
                for (int cj = 0; cj < 8; cj++) {
                    int n = cj * 16 + c16;
                    L[cj] = (n < K_CL) ? invT * acc[ri][cj][reg] : -3.0e38f;
                    lmax = fmaxf(lmax, L[cj]);
                }
#pragma unroll
                for (int w = 1; w < 16; w <<= 1) lmax = fmaxf(lmax, __shfl_xor(lmax, w, 64));
                float se = 0.f, lsel = 0.f;
#pragma unroll
                for (int cj = 0; cj < 8; cj++) {
                    int n = cj * 16 + c16;
                    if (n < K_CL) {
                        se += __expf(L[cj] - lmax);
                        if (n == lbl) lsel = L[cj];
                    }
                }
#pragma unroll
                for (int w = 1; w < 16; w <<= 1) {
                    se   += __shfl_xor(se,   w, 64);
                    lsel += __shfl_xor(lsel, w, 64);
                }
                if (c16 == 0) th_loss += (lmax + __logf(se)) - lsel;
            }
        }
#pragma unroll
        for (int w = 1; w < 64; w <<= 1) th_loss += __shfl_xor(th_loss, w, 64);
        if (lane == 0) red[wave] = th_loss;
        __syncthreads();
        if (tid == 0) part[blockIdx.x] = red[0] + red[1] + red[2] + red[3];
    }
}

// ---------------------------------------------------------------------------
// accum as MFMA GEMM: sums[c][d] = sum_p onehot[c][p] * x[p][d]
// A = onehot (built from cl, bf16 1.0/0.0), B = x tile (k-major u16 reads).
// Wave w owns clusters w*32..w*32+31; acc held across TPB_ACC tiles; one
// global-atomic flush per block.  grid 512 x 256
template<bool BF>
__global__ __launch_bounds__(256) void accum_gemm_kernel(
    const float* __restrict__ xf, const unsigned short* __restrict__ xb,
    const int* __restrict__ cl,
    float* __restrict__ sums, float* __restrict__ counts)
{
    __shared__ unsigned short xs[128 * AST];
    __shared__ int   cl_s[128];
    __shared__ float s_c[128];

    int tid  = threadIdx.x;
    int lane = tid & 63, w = tid >> 6;
    int q = lane >> 4, c16 = lane & 15;
    if (tid < 128) s_c[tid] = 0.f;

    int mcl0 = w * 32 + c16, mcl1 = mcl0 + 16;

    floatx4 acc[2][8];
#pragma unroll
    for (int mt = 0; mt < 2; mt++)
#pragma unroll
        for (int nt = 0; nt < 8; nt++) acc[mt][nt] = (floatx4){0.f, 0.f, 0.f, 0.f};

    for (int t = 0; t < TPB_ACC; t++) {
        long base = ((long)blockIdx.x * TPB_ACC + t) * 128;
        __syncthreads();                        // prev tile fully consumed
        if (BF) {
#pragma unroll
            for (int l = 0; l < 8; l++) {       // 128 rows x 16 chunks of 16B
                int idx = tid + 256 * l;
                int m = idx >> 4, k8 = idx & 15;
                int4 v = *(const int4*)(xb + (base + m) * D + k8 * 8);
                *(int4*)(&xs[m * AST + k8 * 8]) = v;
            }
        } else {
#pragma unroll
            for (int l = 0; l < 16; l++) {      // 128 rows x 32 float4 chunks
                int idx = tid + 256 * l;
                int m = idx >> 5, k4 = idx & 31;
                float4 v = *(const float4*)(xf + (base + m) * D + k4 * 4);
                uint2 ww;
                ww.x = (unsigned)f2bf(v.x) | ((unsigned)f2bf(v.y) << 16);
                ww.y = (unsigned)f2bf(v.z) | ((unsigned)f2bf(v.w) << 16);
                *(uint2*)(&xs[m * AST + k4 * 4]) = ww;
            }
        }
        if (tid < 128) {
            int cv = cl[base + tid];
            cl_s[tid] = cv;
            atomicAdd(&s_c[cv], 1.0f);          // LDS; ~1 hit/cluster/tile
        }
        __syncthreads();
#pragma unroll
        for (int s = 0; s < 4; s++) {           // K = 128 points, chunks of 32
            int kbase = s * 32 + q * 8;
            int4 cA = *(const int4*)(&cl_s[kbase]);
            int4 cB = *(const int4*)(&cl_s[kbase + 4]);
            int cls[8] = {cA.x, cA.y, cA.z, cA.w, cB.x, cB.y, cB.z, cB.w};
            bf16x8 a0, a1;
#pragma unroll
            for (int j = 0; j < 8; j++) {
                a0[j] = (cls[j] == mcl0) ? (short)0x3F80 : (short)0;
                a1[j] = (cls[j] == mcl1) ? (short)0x3F80 : (short)0;
            }
#pragma unroll
            for (int nt = 0; nt < 8; nt++) {
                bf16x8 b;
#pragma unroll
                for (int j = 0; j < 8; j++)
                    b[j] = (short)xs[(kbase + j) * AST + nt * 16 + c16];
                acc[0][nt] = __builtin_amdgcn_mfma_f32_16x16x32_bf16(a0, b, acc[0][nt], 0, 0, 0);
                acc[1][nt] = __builtin_amdgcn_mfma_f32_16x16x32_bf16(a1, b, acc[1][nt], 0, 0, 0);
            }
        }
    }
    __syncthreads();
    // flush: C/D row m = q*4+reg -> cluster; col n = nt*16+c16 -> dim
#pragma unroll
    for (int mt = 0; mt < 2; mt++) {
#pragma unroll
        for (int nt = 0; nt < 8; nt++) {
#pragma unroll
            for (int reg = 0; reg < 4; reg++) {
                int cluster = w * 32 + mt * 16 + q * 4 + reg;
                int dim = nt * 16 + c16;
                unsafeAtomicAdd(&sums[cluster * D + dim], acc[mt][nt][reg]);
            }
        }
    }
    if (tid < 128) unsafeAtomicAdd(&counts[tid], s_c[tid]);
}

// ---------------------------------------------------------------------------
// update: c = sums/max(cnt,1-if-0); bf16 copy + csq; re-zero sums/counts.
__global__ __launch_bounds__(128) void update_kernel(
    unsigned short* __restrict__ cb, float* __restrict__ csq,
    float* __restrict__ sums, float* __restrict__ counts)
{
    int j = blockIdx.x, d = threadIdx.x;
    float cnt = counts[j];
    float div = (cnt == 0.f) ? 1.f : cnt;
    float v = sums[j * D + d] / div;
    cb[j * D + d] = f2bf(v);
    sums[j * D + d] = 0.f;
    float sq = v * v;
#pragma unroll
    for (int w = 1; w < 64; w <<= 1) sq += __shfl_xor(sq, w, 64);
    __shared__ float tmp[2];
    if ((d & 63) == 0) tmp[d >> 6] = sq;
    __syncthreads();
    if (d == 0) { csq[j] = tmp[0] + tmp[1]; counts[j] = 0.f; }
}

// ---------------------------------------------------------------------------
__global__ __launch_bounds__(256) void final_kernel(
    const float* __restrict__ part, float* __restrict__ out)
{
    int tid = threadIdx.x;
    float s = 0.f;
#pragma unroll
    for (int k = 0; k < 16; k++) s += part[tid + 256 * k];
#pragma unroll
    for (int w = 1; w < 64; w <<= 1) s += __shfl_xor(s, w, 64);
    __shared__ float tmp[4];
    if ((tid & 63) == 0) tmp[tid >> 6] = s;
    __syncthreads();
    if (tid == 0)
        out[0] = (tmp[0] + tmp[1] + tmp[2] + tmp[3]) * (0.5f / (float)N_PTS);
}

// ---------------------------------------------------------------------------
extern "C" void kernel_launch(void* const* d_in, const int* in_sizes, int n_in,
                              void* d_out, int out_size, void* d_ws, size_t ws_size,
                              hipStream_t stream)
{
    const float* f1 = (const float*)d_in[0];
    const float* f2 = (const float*)d_in[1];
    float* out = (float*)d_out;

    char* ws = (char*)d_ws;
    char* ws0 = ws;
    unsigned short* cb1 = (unsigned short*)ws; ws += K_CL * D * sizeof(short);
    unsigned short* cb2 = (unsigned short*)ws; ws += K_CL * D * sizeof(short);
    float* csq1 = (float*)ws; ws += 128 * sizeof(float);
    float* csq2 = (float*)ws; ws += 128 * sizeof(float);
    float* sums = (float*)ws; ws += 128 * D * sizeof(float);   // 128 rows (padded)
    float* cnts = (float*)ws; ws += 128 * sizeof(float);       // contiguous w/ sums
    float* part = (float*)ws; ws += 4096 * sizeof(float);
    int* cl1    = (int*)ws;   ws += (size_t)N_PTS * sizeof(int);
    int* cl2    = (int*)ws;   ws += (size_t)N_PTS * sizeof(int);
    unsigned short* xb1 = (unsigned short*)ws; ws += (size_t)N_PTS * D * sizeof(short);
    unsigned short* xb2 = (unsigned short*)ws; ws += (size_t)N_PTS * D * sizeof(short);
    bool usebf = ((size_t)(ws - ws0) <= ws_size);

    hipMemsetAsync(sums, 0, (128 * D + 128) * sizeof(float), stream);
    init_kernel<<<240, 128, 0, stream>>>(f1, f2, cb1, cb2, csq1, csq2);
    if (usebf)
        convert_kernel<<<2048, 256, 0, stream>>>(f1, f2, xb1, xb2);

    if (usebf) {
        for (int it = 0; it < 5; ++it) {
            gemm_kernel<false, true><<<N_PTS / 128, 256, 0, stream>>>(f1, xb1, cb1, csq1, cl1, nullptr);
            accum_gemm_kernel<true><<<512, 256, 0, stream>>>(f1, xb1, cl1, sums, cnts);
            update_kernel<<<K_CL, 128, 0, stream>>>(cb1, csq1, sums, cnts);

            gemm_kernel<false, true><<<N_PTS / 128, 256, 0, stream>>>(f2, xb2, cb2, csq2, cl2, nullptr);
            accum_gemm_kernel<true><<<512, 256, 0, stream>>>(f2, xb2, cl2, sums, cnts);
            update_kernel<<<K_CL, 128, 0, stream>>>(cb2, csq2, sums, cnts);
        }
        gemm_kernel<true, true><<<N_PTS / 128, 256, 0, stream>>>(f1, xb1, cb2, nullptr, cl2, part);
        gemm_kernel<true, true><<<N_PTS / 128, 256, 0, stream>>>(f2, xb2, cb1, nullptr, cl1, part + 2048);
    } else {
        for (int it = 0; it < 5; ++it) {
            gemm_kernel<false, false><<<N_PTS / 128, 256, 0, stream>>>(f1, nullptr, cb1, csq1, cl1, nullptr);
            accum_gemm_kernel<false><<<512, 256, 0, stream>>>(f1, nullptr, cl1, sums, cnts);
            update_kernel<<<K_CL, 128, 0, stream>>>(cb1, csq1, sums, cnts);

            gemm_kernel<false, false><<<N_PTS / 128, 256, 0, stream>>>(f2, nullptr, cb2, csq2, cl2, nullptr);
            accum_gemm_kernel<false><<<512, 256, 0, stream>>>(f2, nullptr, cl2, sums, cnts);
            update_kernel<<<K_CL, 128, 0, stream>>>(cb2, csq2, sums, cnts);
        }
        gemm_kernel<true, false><<<N_PTS / 128, 256, 0, stream>>>(f1, nullptr, cb2, nullptr, cl2, part);
        gemm_kernel<true, false><<<N_PTS / 128, 256, 0, stream>>>(f2, nullptr, cb1, nullptr, cl1, part + 2048);
    }
    final_kernel<<<1, 256, 0, stream>>>(part, out);
}

// Round 4
// 1214.820 us; speedup vs baseline: 6.8612x; 1.0730x over previous
//
#include <hip/hip_runtime.h>
#include <math.h>

#define N_PTS 262144
#define D 128
#define K_CL 120
#define XST 136   // xs stride (u16): 272 B rows, 16B-aligned; blocks XOR-swizzled
#define CST 72    // cs chunk stride (u16) for 64-dim chunks (m92-verified pattern)
#define LST 72    // CE kernel LDS stride (unchanged from R3)

typedef short bf16x8 __attribute__((ext_vector_type(8)));
typedef float floatx4 __attribute__((ext_vector_type(4)));

__device__ __forceinline__ unsigned f2bf(float f) {
    unsigned u = __float_as_uint(f);
    u += 0x7fffu + ((u >> 16) & 1u);   // RNE
    return u >> 16;
}

// ---------------------------------------------------------------------------
// init: cb = bf16(x[:120]), csq = rowwise sumsq (fp32).  grid 240 x 128
__global__ __launch_bounds__(128) void init_kernel(
    const float* __restrict__ f1, const float* __restrict__ f2,
    unsigned short* __restrict__ cb1, unsigned short* __restrict__ cb2,
    float* __restrict__ csq1, float* __restrict__ csq2)
{
    int b = blockIdx.x;
    const float* src = (b < K_CL) ? f1 : f2;
    unsigned short* cb = (b < K_CL) ? cb1 : cb2;
    float* dsq          = (b < K_CL) ? csq1 : csq2;
    int j = (b < K_CL) ? b : (b - K_CL);
    int d = threadIdx.x;
    float v = src[(long)j * D + d];
    cb[j * D + d] = (unsigned short)f2bf(v);
    float sq = v * v;
#pragma unroll
    for (int w = 1; w < 64; w <<= 1) sq += __shfl_xor(sq, w, 64);
    __shared__ float tmp[2];
    if ((d & 63) == 0) tmp[d >> 6] = sq;
    __syncthreads();
    if (d == 0) dsq[j] = tmp[0] + tmp[1];
}

// ---------------------------------------------------------------------------
// fused assign+accumulate.  grid 512 x 256, 4 tiles of 128 points per block.
// Phase 1 (score): S_T[cluster][point] = C.X^T via MFMA, both frags b128 reads.
//   argmin epilogue -> cl, cl_s, s_c.
// Phase 2 (accum): sums[cluster][dim] += onehot.X via MFMA; onehot built in
//   regs from cl_s; B-frags u16 reads made conflict-free by XOR block swizzle.
// MODE: 0 = fp32 input; 1 = fp32 input + write bf16 copy to xb; 2 = bf16 input.
template<int MODE>
__global__ __launch_bounds__(256, 2) void fused_kernel(
    const float* __restrict__ xf, unsigned short* __restrict__ xb,
    const unsigned short* __restrict__ cb, const float* __restrict__ csq,
    int* __restrict__ cl, float* __restrict__ sums, float* __restrict__ counts)
{
    __shared__ unsigned short xs[128 * XST];
    __shared__ unsigned short cs[128 * CST];
    __shared__ float scs[128];
    __shared__ int   cl_s[128];
    __shared__ float s_c[128];

    int tid = threadIdx.x, lane = tid & 63, w = tid >> 6;
    int q = lane >> 4, c16 = lane & 15;
    int hi = c16 >> 3, lo = c16 & 7;

    if (tid < 128) { scs[tid] = (tid < K_CL) ? csq[tid] : 3.0e38f; s_c[tid] = 0.f; }

    floatx4 acc[2][8];                  // accum: clusters w*32+{0,16}.., dims 8x16
#pragma unroll
    for (int mt = 0; mt < 2; mt++)
#pragma unroll
        for (int nt = 0; nt < 8; nt++) acc[mt][nt] = (floatx4){0.f, 0.f, 0.f, 0.f};

    for (int t = 0; t < 4; t++) {
        long base = ((long)blockIdx.x * 4 + t) * 128;
        __syncthreads();                // prev tile's xs/cl_s reads complete
        // ---- stage xs: 128 rows x 128 dims bf16, XOR-swizzled 8-elem blocks
#pragma unroll
        for (int l = 0; l < 8; l++) {
            int idx = tid + 256 * l;    // 0..2047
            int m = idx >> 4, k8 = idx & 15;
            int soff = m * XST + ((k8 ^ ((m >> 3) & 7)) << 3);
            if (MODE == 2) {
                int4 v = *(const int4*)(xb + (long)(base + m) * D + k8 * 8);
                *(int4*)(&xs[soff]) = v;
            } else {
                const float4* p = (const float4*)(xf + (long)(base + m) * D + k8 * 8);
                float4 v0 = p[0], v1 = p[1];
                int4 wv;
                wv.x = (int)(f2bf(v0.x) | (f2bf(v0.y) << 16));
                wv.y = (int)(f2bf(v0.z) | (f2bf(v0.w) << 16));
                wv.z = (int)(f2bf(v1.x) | (f2bf(v1.y) << 16));
                wv.w = (int)(f2bf(v1.z) | (f2bf(v1.w) << 16));
                *(int4*)(&xs[soff]) = wv;
                if (MODE == 1)
                    *(int4*)(xb + (long)(base + m) * D + k8 * 8) = wv;
            }
        }
        // ---- score phase
        floatx4 sacc[8][2];
#pragma unroll
        for (int mt = 0; mt < 8; mt++)
#pragma unroll
            for (int nt = 0; nt < 2; nt++) sacc[mt][nt] = (floatx4){0.f, 0.f, 0.f, 0.f};

#pragma unroll
        for (int half = 0; half < 2; half++) {
            // stage cs chunk: 128 clusters x 64 dims (pad >=K_CL with 0)
#pragma unroll
            for (int l = 0; l < 4; l++) {
                int idx = tid + 256 * l;     // 0..1023
                int n = idx >> 3, k8 = idx & 7;
                int4 v = make_int4(0, 0, 0, 0);
                if (n < K_CL) v = *(const int4*)(cb + n * D + half * 64 + k8 * 8);
                *(int4*)(&cs[n * CST + k8 * 8]) = v;
            }
            __syncthreads();                 // xs + cs chunk ready
#pragma unroll
            for (int s = 0; s < 2; s++) {
                bf16x8 b[2];
#pragma unroll
                for (int nt = 0; nt < 2; nt++) {
                    int r = w * 32 + nt * 16 + c16;
                    int kb = half * 8 + s * 4 + q;
                    b[nt] = *(const bf16x8*)(&xs[r * XST + ((kb ^ ((r >> 3) & 7)) << 3)]);
                }
#pragma unroll
                for (int mt = 0; mt < 8; mt++) {
                    bf16x8 a = *(const bf16x8*)(&cs[(mt * 16 + c16) * CST + s * 32 + q * 8]);
#pragma unroll
                    for (int nt = 0; nt < 2; nt++)
                        sacc[mt][nt] = __builtin_amdgcn_mfma_f32_16x16x32_bf16(
                            a, b[nt], sacc[mt][nt], 0, 0, 0);
                }
            }
            __syncthreads();                 // chunk reads done (before restage/epilogue)
        }
        // ---- argmin epilogue: score = csq[c] - 2*dot; C/D col=point, row=cluster
#pragma unroll
        for (int nt = 0; nt < 2; nt++) {
            float best = 3.9e38f; int bi = 0;
#pragma unroll
            for (int mt = 0; mt < 8; mt++) {
                float4 sv = *(const float4*)(&scs[mt * 16 + q * 4]);
                int nb = mt * 16 + q * 4;
                float s0 = sv.x - 2.f * sacc[mt][nt][0];
                if (s0 < best) { best = s0; bi = nb + 0; }
                float s1 = sv.y - 2.f * sacc[mt][nt][1];
                if (s1 < best) { best = s1; bi = nb + 1; }
                float s2 = sv.z - 2.f * sacc[mt][nt][2];
                if (s2 < best) { best = s2; bi = nb + 2; }
                float s3 = sv.w - 2.f * sacc[mt][nt][3];
                if (s3 < best) { best = s3; bi = nb + 3; }
            }
#pragma unroll
            for (int wm = 16; wm <= 32; wm <<= 1) {
                float ov = __shfl_xor(best, wm, 64);
                int   oi = __shfl_xor(bi,   wm, 64);
                if (ov < best || (ov == best && oi < bi)) { best = ov; bi = oi; }
            }
            if (q == 0) {
                int p = w * 32 + nt * 16 + c16;
                cl_s[p] = bi;
                cl[base + p] = bi;
                atomicAdd(&s_c[bi], 1.0f);
            }
        }
        __syncthreads();                     // cl_s ready for accum
        // ---- accum phase: A = onehot (regs), B = xs dims (swizzled u16 reads)
        int mcl0 = w * 32 + c16, mcl1 = mcl0 + 16;
#pragma unroll
        for (int s = 0; s < 4; s++) {
            int kbase = s * 32 + q * 8;
            int4 cA = *(const int4*)(&cl_s[kbase]);
            int4 cB = *(const int4*)(&cl_s[kbase + 4]);
            int cls[8] = {cA.x, cA.y, cA.z, cA.w, cB.x, cB.y, cB.z, cB.w};
            bf16x8 a0, a1;
#pragma unroll
            for (int j = 0; j < 8; j++) {
                a0[j] = (cls[j] == mcl0) ? (short)0x3F80 : (short)0;
                a1[j] = (cls[j] == mcl1) ? (short)0x3F80 : (short)0;
            }
            int sw = (s * 4 + q) & 7;
#pragma unroll
            for (int nt = 0; nt < 8; nt++) {
                int blk = ((((nt * 2) + hi) ^ sw) << 3) + lo;
                bf16x8 b;
#pragma unroll
                for (int j = 0; j < 8; j++)
                    b[j] = (short)xs[(kbase + j) * XST + blk];
                acc[0][nt] = __builtin_amdgcn_mfma_f32_16x16x32_bf16(a0, b, acc[0][nt], 0, 0, 0);
                acc[1][nt] = __builtin_amdgcn_mfma_f32_16x16x32_bf16(a1, b, acc[1][nt], 0, 0, 0);
            }
        }
    }
    __syncthreads();                         // s_c complete
    // ---- flush: C/D row=cluster-in-Mtile, col=dim
#pragma unroll
    for (int mt = 0; mt < 2; mt++)
#pragma unroll
        for (int nt = 0; nt < 8; nt++)
#pragma unroll
            for (int reg = 0; reg < 4; reg++) {
                int cluster = w * 32 + mt * 16 + q * 4 + reg;
                int dim = nt * 16 + c16;
                unsafeAtomicAdd(&sums[cluster * D + dim], acc[mt][nt][reg]);
            }
    if (tid < 128) unsafeAtomicAdd(&counts[tid], s_c[tid]);
}

// ---------------------------------------------------------------------------
// CE: loss_i = logsumexp(x_i.C^T/T) - x_i.c[label]/T; block partial -> part.
// grid 2048 x 256 (R3 structure, CE-only).
template<bool BF>
__global__ __launch_bounds__(256) void ce_kernel(
    const float* __restrict__ xf, const unsigned short* __restrict__ xb,
    const unsigned short* __restrict__ cb,
    const int* __restrict__ cl, float* __restrict__ part)
{
    __shared__ unsigned short xsm[128 * LST];
    __shared__ unsigned short csm[128 * LST];
    __shared__ float red[4];

    int tid  = threadIdx.x;
    int lane = tid & 63, wave = tid >> 6;
    int q = lane >> 4, c16 = lane & 15;
    long base = (long)blockIdx.x * 128;

    floatx4 acc[2][8];
#pragma unroll
    for (int ri = 0; ri < 2; ri++)
#pragma unroll
        for (int cj = 0; cj < 8; cj++) acc[ri][cj] = (floatx4){0.f, 0.f, 0.f, 0.f};

    for (int kc = 0; kc < D; kc += 64) {
        __syncthreads();
#pragma unroll
        for (int l = 0; l < 8; l++) {
            int idx = tid + 256 * l;
            int m = idx >> 4, k4 = idx & 15;
            uint2 wv;
            if (BF) {
                wv = *(const uint2*)(xb + (base + m) * D + kc + k4 * 4);
            } else {
                float4 v = *(const float4*)(xf + (base + m) * D + kc + k4 * 4);
                wv.x = f2bf(v.x) | (f2bf(v.y) << 16);
                wv.y = f2bf(v.z) | (f2bf(v.w) << 16);
            }
            *(uint2*)(&xsm[m * LST + k4 * 4]) = wv;
        }
#pragma unroll
        for (int l = 0; l < 8; l++) {
            int idx = tid + 256 * l;
            int n = idx >> 4, k4 = idx & 15;
            uint2 wv = make_uint2(0u, 0u);
            if (n < K_CL) wv = *(const uint2*)(cb + (long)n * D + kc + k4 * 4);
            *(uint2*)(&csm[n * LST + k4 * 4]) = wv;
        }
        __syncthreads();
#pragma unroll
        for (int s = 0; s < 2; s++) {
            int kk = s * 32 + q * 8;
            bf16x8 a[2], b[8];
#pragma unroll
            for (int ri = 0; ri < 2; ri++)
                a[ri] = *(const bf16x8*)(&xsm[(wave * 32 + ri * 16 + c16) * LST + kk]);
#pragma unroll
            for (int cj = 0; cj < 8; cj++)
                b[cj] = *(const bf16x8*)(&csm[(cj * 16 + c16) * LST + kk]);
#pragma unroll
            for (int ri = 0; ri < 2; ri++)
#pragma unroll
                for (int cj = 0; cj < 8; cj++)
                    acc[ri][cj] = __builtin_amdgcn_mfma_f32_16x16x32_bf16(
                        a[ri], b[cj], acc[ri][cj], 0, 0, 0);
        }
    }

    const float invT = 2.5f;
    float th_loss = 0.f;
#pragma unroll
    for (int ri = 0; ri < 2; ri++) {
#pragma unroll
        for (int reg = 0; reg < 4; reg++) {
            long m = base + wave * 32 + ri * 16 + q * 4 + reg;
            int lbl = cl[m];
            float L[8];
            float lmax = -3.0e38f;
#pragma unroll
            for (int cj = 0; cj < 8; cj++) {
                int n = cj * 16 + c16;
                L[cj] = (n < K_CL) ? invT * acc[ri][cj][reg] : -3.0e38f;
                lmax = fmaxf(lmax, L[cj]);
            }
#pragma unroll
            for (int w = 1; w < 16; w <<= 1) lmax = fmaxf(lmax, __shfl_xor(lmax, w, 64));
            float se = 0.f, lsel = 0.f;
#pragma unroll
            for (int cj = 0; cj < 8; cj++) {
                int n = cj * 16 + c16;
                if (n < K_CL) {
                    se += __expf(L[cj] - lmax);
                    if (n == lbl) lsel = L[cj];
                }
            }
#pragma unroll
            for (int w = 1; w < 16; w <<= 1) {
                se   += __shfl_xor(se,   w, 64);
                lsel += __shfl_xor(lsel, w, 64);
            }
            if (c16 == 0) th_loss += (lmax + __logf(se)) - lsel;
        }
    }
#pragma unroll
    for (int w = 1; w < 64; w <<= 1) th_loss += __shfl_xor(th_loss, w, 64);
    if (lane == 0) red[wave] = th_loss;
    __syncthreads();
    if (tid == 0) part[blockIdx.x] = red[0] + red[1] + red[2] + red[3];
}

// ---------------------------------------------------------------------------
// update: c = sums/max(cnt,1-if-0); bf16 copy + csq; re-zero sums/counts.
__global__ __launch_bounds__(128) void update_kernel(
    unsigned short* __restrict__ cb, float* __restrict__ csq,
    float* __restrict__ sums, float* __restrict__ counts)
{
    int j = blockIdx.x, d = threadIdx.x;
    float cnt = counts[j];
    float div = (cnt == 0.f) ? 1.f : cnt;
    float v = sums[j * D + d] / div;
    cb[j * D + d] = (unsigned short)f2bf(v);
    sums[j * D + d] = 0.f;
    float sq = v * v;
#pragma unroll
    for (int w = 1; w < 64; w <<= 1) sq += __shfl_xor(sq, w, 64);
    __shared__ float tmp[2];
    if ((d & 63) == 0) tmp[d >> 6] = sq;
    __syncthreads();
    if (d == 0) { csq[j] = tmp[0] + tmp[1]; counts[j] = 0.f; }
}

// ---------------------------------------------------------------------------
__global__ __launch_bounds__(256) void final_kernel(
    const float* __restrict__ part, float* __restrict__ out)
{
    int tid = threadIdx.x;
    float s = 0.f;
#pragma unroll
    for (int k = 0; k < 16; k++) s += part[tid + 256 * k];
#pragma unroll
    for (int w = 1; w < 64; w <<= 1) s += __shfl_xor(s, w, 64);
    __shared__ float tmp[4];
    if ((tid & 63) == 0) tmp[tid >> 6] = s;
    __syncthreads();
    if (tid == 0)
        out[0] = (tmp[0] + tmp[1] + tmp[2] + tmp[3]) * (0.5f / (float)N_PTS);
}

// ---------------------------------------------------------------------------
extern "C" void kernel_launch(void* const* d_in, const int* in_sizes, int n_in,
                              void* d_out, int out_size, void* d_ws, size_t ws_size,
                              hipStream_t stream)
{
    const float* f1 = (const float*)d_in[0];
    const float* f2 = (const float*)d_in[1];
    float* out = (float*)d_out;

    char* ws = (char*)d_ws;
    char* ws0 = ws;
    unsigned short* cb1 = (unsigned short*)ws; ws += K_CL * D * sizeof(short);
    unsigned short* cb2 = (unsigned short*)ws; ws += K_CL * D * sizeof(short);
    float* csq1 = (float*)ws; ws += 128 * sizeof(float);
    float* csq2 = (float*)ws; ws += 128 * sizeof(float);
    float* sums = (float*)ws; ws += 128 * D * sizeof(float);
    float* cnts = (float*)ws; ws += 128 * sizeof(float);      // contiguous w/ sums
    float* part = (float*)ws; ws += 4096 * sizeof(float);
    int* cl1    = (int*)ws;   ws += (size_t)N_PTS * sizeof(int);
    int* cl2    = (int*)ws;   ws += (size_t)N_PTS * sizeof(int);
    unsigned short* xb1 = (unsigned short*)ws; ws += (size_t)N_PTS * D * sizeof(short);
    unsigned short* xb2 = (unsigned short*)ws; ws += (size_t)N_PTS * D * sizeof(short);
    bool usebf = ((size_t)(ws - ws0) <= ws_size);

    hipMemsetAsync(sums, 0, (128 * D + 128) * sizeof(float), stream);
    init_kernel<<<240, 128, 0, stream>>>(f1, f2, cb1, cb2, csq1, csq2);

    if (usebf) {
        // iter 0: stage from fp32, emit bf16 copies as a side effect
        fused_kernel<1><<<512, 256, 0, stream>>>(f1, xb1, cb1, csq1, cl1, sums, cnts);
        update_kernel<<<K_CL, 128, 0, stream>>>(cb1, csq1, sums, cnts);
        fused_kernel<1><<<512, 256, 0, stream>>>(f2, xb2, cb2, csq2, cl2, sums, cnts);
        update_kernel<<<K_CL, 128, 0, stream>>>(cb2, csq2, sums, cnts);
        for (int it = 1; it < 5; ++it) {
            fused_kernel<2><<<512, 256, 0, stream>>>(nullptr, xb1, cb1, csq1, cl1, sums, cnts);
            update_kernel<<<K_CL, 128, 0, stream>>>(cb1, csq1, sums, cnts);
            fused_kernel<2><<<512, 256, 0, stream>>>(nullptr, xb2, cb2, csq2, cl2, sums, cnts);
            update_kernel<<<K_CL, 128, 0, stream>>>(cb2, csq2, sums, cnts);
        }
        ce_kernel<true><<<N_PTS / 128, 256, 0, stream>>>(f1, xb1, cb2, cl2, part);
        ce_kernel<true><<<N_PTS / 128, 256, 0, stream>>>(f2, xb2, cb1, cl1, part + 2048);
    } else {
        for (int it = 0; it < 5; ++it) {
            fused_kernel<0><<<512, 256, 0, stream>>>(f1, nullptr, cb1, csq1, cl1, sums, cnts);
            update_kernel<<<K_CL, 128, 0, stream>>>(cb1, csq1, sums, cnts);
            fused_kernel<0><<<512, 256, 0, stream>>>(f2, nullptr, cb2, csq2, cl2, sums, cnts);
            update_kernel<<<K_CL, 128, 0, stream>>>(cb2, csq2, sums, cnts);
        }
        ce_kernel<false><<<N_PTS / 128, 256, 0, stream>>>(f1, nullptr, cb2, cl2, part);
        ce_kernel<false><<<N_PTS / 128, 256, 0, stream>>>(f2, nullptr, cb1, cl1, part + 2048);
    }
    final_kernel<<<1, 256, 0, stream>>>(part, out);
}